// Round 1
// baseline (170.789 us; speedup 1.0000x reference)
//
#include <hip/hip_runtime.h>

// mixture/target/noise: (N, 2, C, T, F) float32
#define Nn 4
#define Cc 8
#define Tt 256
#define Ff 513
#define TFs (Tt * Ff)      // 131328
#define NCHUNK 16
#define TCHUNK (Tt / NCHUNK)

// ---------------------------------------------------------------------------
// Stage 1: partial covariances. ONE block computes ALL 36 Hermitian pairs,
// so every input element is read exactly once (was 3.25x with 4 pair-groups).
// 72 f32 accumulators + 16 live loads fits VGPR budget at 64 threads/block.
// Partial layout: [inp][n][chunk][p][ri][f]  (f contiguous -> coalesced)
// ---------------------------------------------------------------------------
__global__ __launch_bounds__(64) void cov_partial(
    const float* __restrict__ target, const float* __restrict__ noise,
    float* __restrict__ partial)
{
    int f = blockIdx.x * 64 + threadIdx.x;
    if (f >= Ff) return;
    int n = blockIdx.y;
    int z = blockIdx.z;            // z = chunk*2 + inp
    int inp = z & 1;
    int chunk = z >> 1;

    const float* src = inp ? noise : target;
    const float* bt = src + (size_t)n * 2 * Cc * TFs + (size_t)(chunk * TCHUNK) * Ff + f;

    float ar[36], ai[36];
#pragma unroll
    for (int p = 0; p < 36; ++p) { ar[p] = 0.f; ai[p] = 0.f; }

#pragma unroll 2
    for (int tt = 0; tt < TCHUNK; ++tt) {
        float re[8], im[8];
#pragma unroll
        for (int c = 0; c < 8; ++c) {
            re[c] = bt[(size_t)c * TFs];
            im[c] = bt[(size_t)(Cc + c) * TFs];
        }
        int p = 0;
#pragma unroll
        for (int a = 0; a < 8; ++a) {
#pragma unroll
            for (int b = a; b < 8; ++b, ++p) {
                ar[p] += re[a] * re[b] + im[a] * im[b];
                if (a != b)                       // diagonal imag is exactly 0
                    ai[p] += im[a] * re[b] - re[a] * im[b];
            }
        }
        bt += Ff;
    }

    float* dst = partial + (((size_t)inp * Nn + n) * NCHUNK + chunk) * 72 * (size_t)Ff + f;
#pragma unroll
    for (int p = 0; p < 36; ++p) {
        dst[(size_t)(2 * p + 0) * Ff] = ar[p];
        dst[(size_t)(2 * p + 1) * Ff] = ai[p];
    }
}

// ---------------------------------------------------------------------------
// Stage 2: chunk-reduce + wave-parallel MVDR solve. ONE wave per (n,f).
// Lane (r,c) = entry (r,c) of the 8x8 matrices. Gauss-Jordan with partial
// pivoting on [phiN | phiT] -> B ends as G = phiN^{-1} phiT. All cross-lane
// traffic via shuffles: zero barriers in the solve, no serial pivot scan.
// ---------------------------------------------------------------------------
__global__ __launch_bounds__(64) void mvdr_weights(
    const float* __restrict__ partial, const int* __restrict__ ref_ptr,
    float2* __restrict__ wconj)
{
    int f = blockIdx.x;
    int n = blockIdx.y;
    int lane = threadIdx.x;

    __shared__ float cov[144];     // [0..71] = target cov, [72..143] = noise cov

    for (int comp = lane; comp < 144; comp += 64) {
        int inp = comp >= 72;
        int idx = inp ? comp - 72 : comp;
        float s = 0.f;
#pragma unroll
        for (int ch = 0; ch < NCHUNK; ++ch)
            s += partial[((((size_t)inp * Nn + n) * NCHUNK + ch) * 72 + idx) * (size_t)Ff + f];
        cov[comp] = s;
    }
    __syncthreads();

    int r = lane >> 3, c = lane & 7;
    int lo = r < c ? r : c, hi = r < c ? c : r;
    int p = lo * 8 - lo * (lo - 1) / 2 + (hi - lo);
    const float invT = 1.0f / (float)Tt;
    const float dl = 0.001f / 1.41421356237309515f;   // 0.001/sqrt(2)
    float sgn = (r > c) ? -1.f : 1.f;                 // Hermitian reconstruction

    float2 a = make_float2(cov[72 + 2 * p] * invT, sgn * cov[72 + 2 * p + 1] * invT);
    float2 b = make_float2(cov[2 * p] * invT,      sgn * cov[2 * p + 1] * invT);
    if (r == c) { a.x += dl; a.y += dl; }             // complex diagonal loading

    for (int k = 0; k < 8; ++k) {
        // --- argmax |A_{jk}|^2 over j >= k (butterfly over the r dimension) ---
        float mag = (c == k && r >= k) ? (a.x * a.x + a.y * a.y) : -1.f;
        int midx = r;
#pragma unroll
        for (int st = 8; st < 64; st <<= 1) {
            float om = __shfl_xor(mag, st, 64);
            int   oi = __shfl_xor(midx, st, 64);
            if (om > mag) { mag = om; midx = oi; }
        }
        int piv = __shfl(midx, k, 64);                // lane k is (r=0, c=k)

        // --- swap rows k <-> piv ---
        int srcr = (r == k) ? piv : ((r == piv) ? k : r);
        int src = srcr * 8 + c;
        a.x = __shfl(a.x, src, 64); a.y = __shfl(a.y, src, 64);
        b.x = __shfl(b.x, src, 64); b.y = __shfl(b.y, src, 64);

        // --- scale row k by 1/pivot ---
        float pvx = __shfl(a.x, k * 8 + k, 64), pvy = __shfl(a.y, k * 8 + k, 64);
        float d = pvx * pvx + pvy * pvy;
        float ipx = pvx / d, ipy = -pvy / d;
        if (r == k) {
            float2 t = a;
            a = make_float2(t.x * ipx - t.y * ipy, t.x * ipy + t.y * ipx);
            t = b;
            b = make_float2(t.x * ipx - t.y * ipy, t.x * ipy + t.y * ipx);
        }

        // --- eliminate all other rows ---
        float rax = __shfl(a.x, k * 8 + c, 64), ray = __shfl(a.y, k * 8 + c, 64);
        float rbx = __shfl(b.x, k * 8 + c, 64), rby = __shfl(b.y, k * 8 + c, 64);
        float fx  = __shfl(a.x, r * 8 + k, 64), fy  = __shfl(a.y, r * 8 + k, 64);
        if (r != k) {
            a.x -= fx * rax - fy * ray;  a.y -= fx * ray + fy * rax;
            b.x -= fx * rbx - fy * rby;  b.y -= fx * rby + fy * rbx;
        }
    }

    // --- l = trace(G): full-wave sum of diagonal entries of B ---
    float tx = (r == c) ? b.x : 0.f, ty = (r == c) ? b.y : 0.f;
#pragma unroll
    for (int st = 1; st < 64; st <<= 1) {
        tx += __shfl_xor(tx, st, 64);
        ty += __shfl_xor(ty, st, 64);
    }

    int ref = *ref_ptr;
    if (c == ref) {                                   // lane (r, ref) holds G_{r,ref}
        float den = tx * tx + ty * ty;
        float wx = (b.x * tx + b.y * ty) / den;       // W = G[:,ref] / l
        float wy = (b.y * tx - b.x * ty) / den;
        wconj[((size_t)n * Ff + f) * 8 + r] = make_float2(wx, -wy);  // conj(W)
    }
}

// ---------------------------------------------------------------------------
// Stage 3: X_bf(n,t,f) = sum_c conj(W)(n,f,c) * y(n,c,t,f)
// ---------------------------------------------------------------------------
__global__ __launch_bounds__(256) void beamform(
    const float* __restrict__ y, const float2* __restrict__ wconj,
    float* __restrict__ out)
{
    int idx = blockIdx.x * 256 + threadIdx.x;   // < N*T*F = 525312
    int n = idx / TFs;
    int rem = idx - n * TFs;
    int t = rem / Ff;
    int f = rem - t * Ff;

    size_t base_re = (size_t)n * 2 * Cc * TFs + (size_t)t * Ff + f;
    size_t base_im = base_re + (size_t)Cc * TFs;
    const float2* w = wconj + ((size_t)n * Ff + f) * 8;

    float xr = 0.f, xi = 0.f;
#pragma unroll
    for (int c = 0; c < Cc; ++c) {
        float yre = y[base_re + (size_t)c * TFs];
        float yim = y[base_im + (size_t)c * TFs];
        float2 wc = w[c];
        xr += wc.x * yre - wc.y * yim;
        xi += wc.x * yim + wc.y * yre;
    }
    size_t ob = (size_t)n * 2 * TFs + (size_t)t * Ff + f;
    out[ob] = xr;
    out[ob + TFs] = xi;
}

extern "C" void kernel_launch(void* const* d_in, const int* in_sizes, int n_in,
                              void* d_out, int out_size, void* d_ws, size_t ws_size,
                              hipStream_t stream) {
    const float* mixture = (const float*)d_in[0];
    const float* target  = (const float*)d_in[1];
    const float* noise   = (const float*)d_in[2];
    const int*   refp    = (const int*)d_in[3];
    float* out = (float*)d_out;

    // partial: 2 * Nn * NCHUNK * 72 * Ff floats = ~18.9 MB (ws is ~256 MB)
    float*  partial = (float*)d_ws;
    float2* wconj = (float2*)((char*)d_ws +
                              (size_t)2 * Nn * NCHUNK * 72 * Ff * sizeof(float));

    cov_partial<<<dim3(9, Nn, NCHUNK * 2), 64, 0, stream>>>(target, noise, partial);
    mvdr_weights<<<dim3(Ff, Nn), 64, 0, stream>>>(partial, refp, wconj);
    beamform<<<dim3((Nn * TFs) / 256), 256, 0, stream>>>(mixture, wconj, out);
}

// Round 2
// 156.815 us; speedup vs baseline: 1.0891x; 1.0891x over previous
//
#include <hip/hip_runtime.h>

// mixture/target/noise: (N, 2, C, T, F) float32
#define Nn 4
#define Cc 8
#define Tt 256
#define Ff 513
#define TFs (Tt * Ff)      // 131328
#define NCHUNK 32
#define TCHUNK (Tt / NCHUNK)
#define SLAB ((size_t)Ff * 72)   // floats per (inp,n,chunk) slab

// ---------------------------------------------------------------------------
// Stage 1: partial covariances. ONE block computes ALL 36 Hermitian pairs
// (each input element read exactly once). Partial layout is now
// [inp][n][chunk][f][72]: the 72 components of one f are CONTIGUOUS (288 B),
// so stage 2 reads coalesced slabs instead of 64-way scattered cachelines.
// Each lane owns one f -> writes its 72 floats as 18 float4 stores.
// ---------------------------------------------------------------------------
__global__ __launch_bounds__(64) void cov_partial(
    const float* __restrict__ target, const float* __restrict__ noise,
    float* __restrict__ partial)
{
    int f = blockIdx.x * 64 + threadIdx.x;
    if (f >= Ff) return;
    int n = blockIdx.y;
    int z = blockIdx.z;            // z = chunk*2 + inp
    int inp = z & 1;
    int chunk = z >> 1;

    const float* src = inp ? noise : target;
    const float* bt = src + (size_t)n * 2 * Cc * TFs + (size_t)(chunk * TCHUNK) * Ff + f;

    float ar[36], ai[36];
#pragma unroll
    for (int p = 0; p < 36; ++p) { ar[p] = 0.f; ai[p] = 0.f; }

#pragma unroll 2
    for (int tt = 0; tt < TCHUNK; ++tt) {
        float re[8], im[8];
#pragma unroll
        for (int c = 0; c < 8; ++c) {
            re[c] = bt[(size_t)c * TFs];
            im[c] = bt[(size_t)(Cc + c) * TFs];
        }
        int p = 0;
#pragma unroll
        for (int a = 0; a < 8; ++a) {
#pragma unroll
            for (int b = a; b < 8; ++b, ++p) {
                ar[p] += re[a] * re[b] + im[a] * im[b];
                if (a != b)                       // diagonal imag is exactly 0
                    ai[p] += im[a] * re[b] - re[a] * im[b];
            }
        }
        bt += Ff;
    }

    // interleaved [p][ri] within this f's contiguous 288 B slab
    float* dst = partial + (((size_t)inp * Nn + n) * NCHUNK + chunk) * SLAB
                 + (size_t)f * 72;
#pragma unroll
    for (int j = 0; j < 18; ++j) {
        float4 v = make_float4(ar[2 * j], ai[2 * j], ar[2 * j + 1], ai[2 * j + 1]);
        *(float4*)(dst + 4 * j) = v;
    }
}

// ---------------------------------------------------------------------------
// Stage 2: chunk-reduce + wave-parallel MVDR solve. ONE wave per (n,f).
// Lane (r,c) = entry (r,c) of the 8x8 matrices. With the [f][comp] layout a
// lane float2-loads its own (2p,2p+1) pair directly: all 64 lanes of the wave
// read inside the same 288 B window -> ~5 cachelines/instruction, no LDS,
// no barriers anywhere. Gauss-Jordan with partial pivoting on [phiN | phiT]
// ends with B = G = phiN^{-1} phiT; all cross-lane traffic via shuffles.
// ---------------------------------------------------------------------------
__global__ __launch_bounds__(64) void mvdr_weights(
    const float* __restrict__ partial, const int* __restrict__ ref_ptr,
    float2* __restrict__ wconj)
{
    int f = blockIdx.x;
    int n = blockIdx.y;
    int lane = threadIdx.x;

    int r = lane >> 3, c = lane & 7;
    int lo = r < c ? r : c, hi = r < c ? c : r;
    int p = lo * 8 - lo * (lo - 1) / 2 + (hi - lo);

    const float* pT = partial + ((size_t)(0 * Nn + n) * NCHUNK) * SLAB
                      + (size_t)f * 72 + 2 * p;
    const float* pN = partial + ((size_t)(1 * Nn + n) * NCHUNK) * SLAB
                      + (size_t)f * 72 + 2 * p;
    float2 sT = make_float2(0.f, 0.f), sN = make_float2(0.f, 0.f);
#pragma unroll
    for (int ch = 0; ch < NCHUNK; ++ch) {
        float2 vT = *(const float2*)(pT + ch * SLAB);
        float2 vN = *(const float2*)(pN + ch * SLAB);
        sT.x += vT.x; sT.y += vT.y;
        sN.x += vN.x; sN.y += vN.y;
    }

    const float invT = 1.0f / (float)Tt;
    const float dl = 0.001f / 1.41421356237309515f;   // 0.001/sqrt(2)
    float sgn = (r > c) ? -1.f : 1.f;                 // Hermitian reconstruction

    float2 a = make_float2(sN.x * invT, sgn * sN.y * invT);
    float2 b = make_float2(sT.x * invT, sgn * sT.y * invT);
    if (r == c) { a.x += dl; a.y += dl; }             // complex diagonal loading

    for (int k = 0; k < 8; ++k) {
        // --- argmax |A_{jk}|^2 over j >= k (butterfly) ---
        float mag = (c == k && r >= k) ? (a.x * a.x + a.y * a.y) : -1.f;
        int midx = r;
#pragma unroll
        for (int st = 8; st < 64; st <<= 1) {
            float om = __shfl_xor(mag, st, 64);
            int   oi = __shfl_xor(midx, st, 64);
            if (om > mag) { mag = om; midx = oi; }
        }
        int piv = __shfl(midx, k, 64);

        // --- swap rows k <-> piv ---
        int srcr = (r == k) ? piv : ((r == piv) ? k : r);
        int src = srcr * 8 + c;
        a.x = __shfl(a.x, src, 64); a.y = __shfl(a.y, src, 64);
        b.x = __shfl(b.x, src, 64); b.y = __shfl(b.y, src, 64);

        // --- scale row k by 1/pivot ---
        float pvx = __shfl(a.x, k * 8 + k, 64), pvy = __shfl(a.y, k * 8 + k, 64);
        float d = pvx * pvx + pvy * pvy;
        float ipx = pvx / d, ipy = -pvy / d;
        if (r == k) {
            float2 t = a;
            a = make_float2(t.x * ipx - t.y * ipy, t.x * ipy + t.y * ipx);
            t = b;
            b = make_float2(t.x * ipx - t.y * ipy, t.x * ipy + t.y * ipx);
        }

        // --- eliminate all other rows ---
        float rax = __shfl(a.x, k * 8 + c, 64), ray = __shfl(a.y, k * 8 + c, 64);
        float rbx = __shfl(b.x, k * 8 + c, 64), rby = __shfl(b.y, k * 8 + c, 64);
        float fx  = __shfl(a.x, r * 8 + k, 64), fy  = __shfl(a.y, r * 8 + k, 64);
        if (r != k) {
            a.x -= fx * rax - fy * ray;  a.y -= fx * ray + fy * rax;
            b.x -= fx * rbx - fy * rby;  b.y -= fx * rby + fy * rbx;
        }
    }

    // --- l = trace(G): full-wave sum of diagonal entries of B ---
    float tx = (r == c) ? b.x : 0.f, ty = (r == c) ? b.y : 0.f;
#pragma unroll
    for (int st = 1; st < 64; st <<= 1) {
        tx += __shfl_xor(tx, st, 64);
        ty += __shfl_xor(ty, st, 64);
    }

    int ref = *ref_ptr;
    if (c == ref) {                                   // lane (r, ref) holds G_{r,ref}
        float den = tx * tx + ty * ty;
        float wx = (b.x * tx + b.y * ty) / den;       // W = G[:,ref] / l
        float wy = (b.y * tx - b.x * ty) / den;
        wconj[((size_t)n * Ff + f) * 8 + r] = make_float2(wx, -wy);  // conj(W)
    }
}

// ---------------------------------------------------------------------------
// Stage 3: X_bf(n,t,f) = sum_c conj(W)(n,f,c) * y(n,c,t,f)
// ---------------------------------------------------------------------------
__global__ __launch_bounds__(256) void beamform(
    const float* __restrict__ y, const float2* __restrict__ wconj,
    float* __restrict__ out)
{
    int idx = blockIdx.x * 256 + threadIdx.x;   // < N*T*F = 525312
    int n = idx / TFs;
    int rem = idx - n * TFs;
    int t = rem / Ff;
    int f = rem - t * Ff;

    size_t base_re = (size_t)n * 2 * Cc * TFs + (size_t)t * Ff + f;
    size_t base_im = base_re + (size_t)Cc * TFs;
    const float2* w = wconj + ((size_t)n * Ff + f) * 8;

    float xr = 0.f, xi = 0.f;
#pragma unroll
    for (int c = 0; c < Cc; ++c) {
        float yre = y[base_re + (size_t)c * TFs];
        float yim = y[base_im + (size_t)c * TFs];
        float2 wc = w[c];
        xr += wc.x * yre - wc.y * yim;
        xi += wc.x * yim + wc.y * yre;
    }
    size_t ob = (size_t)n * 2 * TFs + (size_t)t * Ff + f;
    out[ob] = xr;
    out[ob + TFs] = xi;
}

extern "C" void kernel_launch(void* const* d_in, const int* in_sizes, int n_in,
                              void* d_out, int out_size, void* d_ws, size_t ws_size,
                              hipStream_t stream) {
    const float* mixture = (const float*)d_in[0];
    const float* target  = (const float*)d_in[1];
    const float* noise   = (const float*)d_in[2];
    const int*   refp    = (const int*)d_in[3];
    float* out = (float*)d_out;

    // partial: 2 * Nn * NCHUNK * Ff * 72 floats = ~37.8 MB (ws is ~256 MB)
    float*  partial = (float*)d_ws;
    float2* wconj = (float2*)((char*)d_ws +
                              (size_t)2 * Nn * NCHUNK * SLAB * sizeof(float));

    cov_partial<<<dim3(9, Nn, NCHUNK * 2), 64, 0, stream>>>(target, noise, partial);
    mvdr_weights<<<dim3(Ff, Nn), 64, 0, stream>>>(partial, refp, wconj);
    beamform<<<dim3((Nn * TFs) / 256), 256, 0, stream>>>(mixture, wconj, out);
}

// Round 3
// 143.936 us; speedup vs baseline: 1.1866x; 1.0895x over previous
//
#include <hip/hip_runtime.h>

// mixture/target/noise: (N, 2, C, T, F) float32
#define Nn 4
#define Cc 8
#define Tt 256
#define Ff 513
#define TFs (Tt * Ff)      // 131328
#define NCHUNK 16
#define TCHUNK (Tt / NCHUNK)        // 16 t-steps per chunk, 4 per wave
#define SLAB ((size_t)Ff * 72)      // floats per (inp,n,chunk) slab

// ---------------------------------------------------------------------------
// Stage 1: partial covariances. 256-thread block = 4 waves; each wave
// accumulates 4 t-steps for the same 64-f range (every input element read
// exactly once), then a 2-region LDS reduce (stride-73 rows: conflict-free)
// combines the 4 waves and one cooperative coalesced store writes the slab.
// Grid (9, N, NCHUNK*2) = 4608 waves (~16/CU) -> 2x the in-flight loads of
// the previous single-wave-block version, and half the partial traffic.
// ---------------------------------------------------------------------------
__global__ __launch_bounds__(256) void cov_partial(
    const float* __restrict__ target, const float* __restrict__ noise,
    float* __restrict__ partial)
{
    int tid = threadIdx.x;
    int lane = tid & 63, wave = tid >> 6;
    int f0 = blockIdx.x * 64;
    int f = f0 + lane;
    int fc = f < Ff ? f : (Ff - 1);        // clamp: no early return (barriers!)
    int n = blockIdx.y;
    int z = blockIdx.z;                    // z = chunk*2 + inp
    int inp = z & 1;
    int chunk = z >> 1;

    const float* src = inp ? noise : target;
    const float* bt = src + (size_t)n * 2 * Cc * TFs
                      + (size_t)(chunk * TCHUNK + wave * 4) * Ff + fc;

    float ar[36], ai[36];
#pragma unroll
    for (int p = 0; p < 36; ++p) { ar[p] = 0.f; ai[p] = 0.f; }

#pragma unroll 2
    for (int tt = 0; tt < 4; ++tt) {
        float re[8], im[8];
#pragma unroll
        for (int c = 0; c < 8; ++c) {
            re[c] = bt[(size_t)c * TFs];
            im[c] = bt[(size_t)(Cc + c) * TFs];
        }
        int p = 0;
#pragma unroll
        for (int a = 0; a < 8; ++a) {
#pragma unroll
            for (int b = a; b < 8; ++b, ++p) {
                ar[p] += re[a] * re[b] + im[a] * im[b];
                if (a != b)                       // diagonal imag is exactly 0
                    ai[p] += im[a] * re[b] - re[a] * im[b];
            }
        }
        bt += Ff;
    }

    // --- 2-region LDS reduce across the 4 waves -----------------------------
    __shared__ float red[2][64][73];       // stride 73 -> (9*l+j)%32 conflict-free
    int reg = wave & 1;
    if (wave < 2) {
        int p = 0;
#pragma unroll
        for (int a = 0; a < 8; ++a)
#pragma unroll
            for (int b = a; b < 8; ++b, ++p) {
                red[reg][lane][2 * p]     = ar[p];
                red[reg][lane][2 * p + 1] = (a == b) ? 0.f : ai[p];
            }
    }
    __syncthreads();
    if (wave >= 2) {
        int p = 0;
#pragma unroll
        for (int a = 0; a < 8; ++a)
#pragma unroll
            for (int b = a; b < 8; ++b, ++p) {
                red[reg][lane][2 * p] += ar[p];
                if (a != b) red[reg][lane][2 * p + 1] += ai[p];
            }
    }
    __syncthreads();

    // --- cooperative coalesced store of the [64 f][72] slab -----------------
    int nf = Ff - f0; if (nf > 64) nf = 64;
    float* dst = partial + (((size_t)inp * Nn + n) * NCHUNK + chunk) * SLAB
                 + (size_t)f0 * 72;
    for (int i = tid; i < nf * 72; i += 256) {
        int fl = i / 72, j = i - fl * 72;
        dst[i] = red[0][fl][j] + red[1][fl][j];
    }
}

// ---------------------------------------------------------------------------
// Stage 2: chunk-reduce + wave-parallel MVDR solve. ONE wave per (n,f).
// Lane (r,c) = entry (r,c); lane float2-loads its pair from each 288 B slab
// window (coalesced), 32 fully-unrolled independent loads. Gauss-Jordan with
// partial pivoting on [phiN | phiT] -> B = G = phiN^{-1} phiT; all cross-lane
// traffic via shuffles, zero barriers.
// ---------------------------------------------------------------------------
__global__ __launch_bounds__(64) void mvdr_weights(
    const float* __restrict__ partial, const int* __restrict__ ref_ptr,
    float2* __restrict__ wconj)
{
    int f = blockIdx.x;
    int n = blockIdx.y;
    int lane = threadIdx.x;

    int r = lane >> 3, c = lane & 7;
    int lo = r < c ? r : c, hi = r < c ? c : r;
    int p = lo * 8 - lo * (lo - 1) / 2 + (hi - lo);

    const float* pT = partial + ((size_t)(0 * Nn + n) * NCHUNK) * SLAB
                      + (size_t)f * 72 + 2 * p;
    const float* pN = partial + ((size_t)(1 * Nn + n) * NCHUNK) * SLAB
                      + (size_t)f * 72 + 2 * p;
    float2 sT = make_float2(0.f, 0.f), sN = make_float2(0.f, 0.f);
#pragma unroll
    for (int ch = 0; ch < NCHUNK; ++ch) {
        float2 vT = *(const float2*)(pT + ch * SLAB);
        float2 vN = *(const float2*)(pN + ch * SLAB);
        sT.x += vT.x; sT.y += vT.y;
        sN.x += vN.x; sN.y += vN.y;
    }

    const float invT = 1.0f / (float)Tt;
    const float dl = 0.001f / 1.41421356237309515f;   // 0.001/sqrt(2)
    float sgn = (r > c) ? -1.f : 1.f;                 // Hermitian reconstruction

    float2 a = make_float2(sN.x * invT, sgn * sN.y * invT);
    float2 b = make_float2(sT.x * invT, sgn * sT.y * invT);
    if (r == c) { a.x += dl; a.y += dl; }             // complex diagonal loading

    for (int k = 0; k < 8; ++k) {
        // --- argmax |A_{jk}|^2 over j >= k (butterfly) ---
        float mag = (c == k && r >= k) ? (a.x * a.x + a.y * a.y) : -1.f;
        int midx = r;
#pragma unroll
        for (int st = 8; st < 64; st <<= 1) {
            float om = __shfl_xor(mag, st, 64);
            int   oi = __shfl_xor(midx, st, 64);
            if (om > mag) { mag = om; midx = oi; }
        }
        int piv = __shfl(midx, k, 64);

        // --- swap rows k <-> piv ---
        int srcr = (r == k) ? piv : ((r == piv) ? k : r);
        int src = srcr * 8 + c;
        a.x = __shfl(a.x, src, 64); a.y = __shfl(a.y, src, 64);
        b.x = __shfl(b.x, src, 64); b.y = __shfl(b.y, src, 64);

        // --- scale row k by 1/pivot ---
        float pvx = __shfl(a.x, k * 8 + k, 64), pvy = __shfl(a.y, k * 8 + k, 64);
        float d = pvx * pvx + pvy * pvy;
        float ipx = pvx / d, ipy = -pvy / d;
        if (r == k) {
            float2 t = a;
            a = make_float2(t.x * ipx - t.y * ipy, t.x * ipy + t.y * ipx);
            t = b;
            b = make_float2(t.x * ipx - t.y * ipy, t.x * ipy + t.y * ipx);
        }

        // --- eliminate all other rows ---
        float rax = __shfl(a.x, k * 8 + c, 64), ray = __shfl(a.y, k * 8 + c, 64);
        float rbx = __shfl(b.x, k * 8 + c, 64), rby = __shfl(b.y, k * 8 + c, 64);
        float fx  = __shfl(a.x, r * 8 + k, 64), fy  = __shfl(a.y, r * 8 + k, 64);
        if (r != k) {
            a.x -= fx * rax - fy * ray;  a.y -= fx * ray + fy * rax;
            b.x -= fx * rbx - fy * rby;  b.y -= fx * rby + fy * rbx;
        }
    }

    // --- l = trace(G): full-wave sum of diagonal entries of B ---
    float tx = (r == c) ? b.x : 0.f, ty = (r == c) ? b.y : 0.f;
#pragma unroll
    for (int st = 1; st < 64; st <<= 1) {
        tx += __shfl_xor(tx, st, 64);
        ty += __shfl_xor(ty, st, 64);
    }

    int ref = *ref_ptr;
    if (c == ref) {                                   // lane (r, ref) holds G_{r,ref}
        float den = tx * tx + ty * ty;
        float wx = (b.x * tx + b.y * ty) / den;       // W = G[:,ref] / l
        float wy = (b.y * tx - b.x * ty) / den;
        wconj[((size_t)n * Ff + f) * 8 + r] = make_float2(wx, -wy);  // conj(W)
    }
}

// ---------------------------------------------------------------------------
// Stage 3: X_bf(n,t,f) = sum_c conj(W)(n,f,c) * y(n,c,t,f)
// ---------------------------------------------------------------------------
__global__ __launch_bounds__(256) void beamform(
    const float* __restrict__ y, const float2* __restrict__ wconj,
    float* __restrict__ out)
{
    int idx = blockIdx.x * 256 + threadIdx.x;   // < N*T*F = 525312
    int n = idx / TFs;
    int rem = idx - n * TFs;
    int t = rem / Ff;
    int f = rem - t * Ff;

    size_t base_re = (size_t)n * 2 * Cc * TFs + (size_t)t * Ff + f;
    size_t base_im = base_re + (size_t)Cc * TFs;
    const float2* w = wconj + ((size_t)n * Ff + f) * 8;

    float xr = 0.f, xi = 0.f;
#pragma unroll
    for (int c = 0; c < Cc; ++c) {
        float yre = y[base_re + (size_t)c * TFs];
        float yim = y[base_im + (size_t)c * TFs];
        float2 wc = w[c];
        xr += wc.x * yre - wc.y * yim;
        xi += wc.x * yim + wc.y * yre;
    }
    size_t ob = (size_t)n * 2 * TFs + (size_t)t * Ff + f;
    out[ob] = xr;
    out[ob + TFs] = xi;
}

extern "C" void kernel_launch(void* const* d_in, const int* in_sizes, int n_in,
                              void* d_out, int out_size, void* d_ws, size_t ws_size,
                              hipStream_t stream) {
    const float* mixture = (const float*)d_in[0];
    const float* target  = (const float*)d_in[1];
    const float* noise   = (const float*)d_in[2];
    const int*   refp    = (const int*)d_in[3];
    float* out = (float*)d_out;

    // partial: 2 * Nn * NCHUNK * Ff * 72 floats = ~18.9 MB (ws is ~256 MB)
    float*  partial = (float*)d_ws;
    float2* wconj = (float2*)((char*)d_ws +
                              (size_t)2 * Nn * NCHUNK * SLAB * sizeof(float));

    cov_partial<<<dim3(9, Nn, NCHUNK * 2), 256, 0, stream>>>(target, noise, partial);
    mvdr_weights<<<dim3(Ff, Nn), 64, 0, stream>>>(partial, refp, wconj);
    beamform<<<dim3((Nn * TFs) / 256), 256, 0, stream>>>(mixture, wconj, out);
}